// Round 9
// baseline (66054.688 us; speedup 1.0000x reference)
//
#include <hip/hip_runtime.h>
#include <math.h>

#define T_STEPS 4096
#define EMB 1024
#define HID 2048
#define CAT 1040
#define TAG 16
#define NBLK 256
#define NTHR 1024

// output offsets (floats)
#define OUT_LOGP 0
#define OUT_PROB (T_STEPS * TAG)
#define OUT_PRED (2 * T_STEPS * TAG)

__device__ __forceinline__ float sigf(float x) { return 1.0f / (1.0f + expf(-x)); }

// epoch-stamped 64-bit payloads: [epoch:32 | value_f32_bits:32].
// Relaxed agent-scope atomics -> serviced at the coherent point; value and
// freshness are ONE atom, so no fences, no drains, no flags anywhere.
__device__ __forceinline__ unsigned long long aload64(const unsigned long long* p) {
  return __hip_atomic_load(p, __ATOMIC_RELAXED, __HIP_MEMORY_SCOPE_AGENT);
}
__device__ __forceinline__ void astore64(unsigned long long* p, unsigned long long v) {
  __hip_atomic_store(p, v, __ATOMIC_RELAXED, __HIP_MEMORY_SCOPE_AGENT);
}
__device__ __forceinline__ unsigned long long pack(unsigned ep, float v) {
  return ((unsigned long long)ep << 32) | (unsigned long long)__float_as_uint(v);
}
__device__ __forceinline__ float val32(unsigned long long v) {
  return __uint_as_float((unsigned)v);
}
__device__ __forceinline__ int epok(unsigned long long v, unsigned ep) {
  return (unsigned)(v >> 32) == ep;
}

// ---- VT[p][i] = W_embed[i][1024+p]  (compact one-hot columns) ----
__global__ __launch_bounds__(256) void rnnss_vt_kernel(const float* __restrict__ We,
                                                       float* __restrict__ VT) {
  int n = blockIdx.x * 256 + threadIdx.x;      // 0..16383
  int p = n >> 10, i = n & 1023;
  VT[n] = We[(size_t)i * CAT + EMB + p];
}

// ---- U[t][i] = sum_k seq[t][k] * W_embed[i][k] + b_embed[i] ----
__global__ __launch_bounds__(256) void rnnss_uprep(const float* __restrict__ X,
                                                   const float* __restrict__ W,
                                                   const float* __restrict__ be,
                                                   float* __restrict__ U) {
  __shared__ __align__(16) float As[32][68];
  __shared__ __align__(16) float Bs[32][68];
  const int bm = blockIdx.x * 64;
  const int bn = blockIdx.y * 64;
  const int tid = threadIdx.x;
  const int tx = tid & 15, ty = tid >> 4;
  const int lr = tid >> 5, lc = tid & 31;
  float acc[4][4] = {};
  for (int k0 = 0; k0 < EMB; k0 += 32) {
#pragma unroll
    for (int p = 0; p < 8; ++p) {
      As[lc][lr + 8 * p] = X[(size_t)(bm + lr + 8 * p) * EMB + k0 + lc];
      Bs[lc][lr + 8 * p] = W[(size_t)(bn + lr + 8 * p) * CAT + k0 + lc];
    }
    __syncthreads();
#pragma unroll 8
    for (int k = 0; k < 32; ++k) {
      const float4 a = *(const float4*)&As[k][ty * 4];
      const float4 v = *(const float4*)&Bs[k][tx * 4];
      float am[4] = {a.x, a.y, a.z, a.w};
      float bv[4] = {v.x, v.y, v.z, v.w};
#pragma unroll
      for (int m = 0; m < 4; ++m)
#pragma unroll
        for (int n = 0; n < 4; ++n) acc[m][n] = fmaf(am[m], bv[n], acc[m][n]);
    }
    __syncthreads();
  }
#pragma unroll
  for (int m = 0; m < 4; ++m)
#pragma unroll
    for (int n = 0; n < 4; ++n)
      U[(size_t)(bm + ty * 4 + m) * EMB + bn + tx * 4 + n] =
          acc[m][n] + be[bn + tx * 4 + n];
}

// ---- persistent LSTM labeler: 256 blocks x 1024 threads ----
// Cross-block sync: NO flags, NO fences, NO drains. Producers store
// epoch-stamped u64 payloads to 2KB-strided lines (parallel at MALL);
// consumers issue coalesced u64 loads of the payload itself and retry until
// all epochs match — the poll IS the gather, one MALL RTT per phase.
//   hp64[k][blk]  (k=0..7):  h value of unit blk*8+k at this step
//   tp64[g][blk]  (g=0..15): block blk's partial for tag g
// Slot-reuse safety: h(t+1) stores are gated on the producer's tp(t) gather;
// tp(t+1) stores are gated on the full h(t+1) gather -> no reader of step t
// can still be in flight when step t+1 overwrites (same chain as R5-R8).
__global__ __launch_bounds__(NTHR, 4) void rnnss_persist(
    const float* __restrict__ Wih, const float* __restrict__ Whh,
    const float* __restrict__ bih, const float* __restrict__ bhh,
    const float* __restrict__ Witm, const float* __restrict__ bitm,
    const float* __restrict__ Wtag, const float* __restrict__ btag,
    const float* __restrict__ U, const float* __restrict__ VT,
    unsigned long long* __restrict__ hp64,  // [8][256], zeroed each call
    unsigned long long* __restrict__ tp64,  // [16][256], zeroed each call
    float* __restrict__ out) {
  __shared__ __align__(16) float sWi[32 * 1024];  // 128 KB: this block's W_ih rows
  __shared__ __align__(16) float se[EMB];
  __shared__ __align__(16) float sh[HID];
  __shared__ float sg[32];     // gate preacts for this block's 8 units
  __shared__ float wpart[16];  // per-wave partials (phase B)
  __shared__ float stv[TAG];   // reduced tag scores
  __shared__ float sc[8];      // persistent cell state (block-owned units)

  const int tid = threadIdx.x;
  const int b = blockIdx.x;
  const int u0 = b * 8;                 // hidden units [u0, u0+8)
  if (tid < 8) sc[tid] = 0.0f;
  sh[tid] = 0.0f;                       // h_0 = 0 (phase A reads sh, never global)
  sh[tid + 1024] = 0.0f;

  // phase A row task: 32 gate rows x 32 lanes
  const int rt = tid >> 5;              // 0..31 : gsec*8 + j
  const int q = tid & 31;
  const int gsec = rt >> 3, j = rt & 7;
  const int grow = gsec * HID + u0 + j;
  const float bsum = bih[grow] + bhh[grow];
  const float4* __restrict__ wh = (const float4*)(Whh + (size_t)grow * HID);

  // phase B row task: 4 interm rows x 256 lanes
  const int brow = tid >> 8, bq = tid & 255;
  const float4* __restrict__ wm = (const float4*)(Witm + (size_t)(b * 4 + brow) * HID);
  float bi0 = 0, bi1 = 0, bi2 = 0, bi3 = 0;
  float wt0 = 0, wt1 = 0, wt2 = 0, wt3 = 0;
  if (tid < TAG) {
    bi0 = bitm[b * 4 + 0];
    bi1 = bitm[b * 4 + 1];
    bi2 = bitm[b * 4 + 2];
    bi3 = bitm[b * 4 + 3];
    wt0 = Wtag[(size_t)tid * 1024 + b * 4 + 0];
    wt1 = Wtag[(size_t)tid * 1024 + b * 4 + 1];
    wt2 = Wtag[(size_t)tid * 1024 + b * 4 + 2];
    wt3 = Wtag[(size_t)tid * 1024 + b * 4 + 3];
  }
  float btw = 0.0f;
  if ((tid & 63) == 0) btw = btag[tid >> 6];

  // ---- prologue: W_ih slice -> LDS (coalesced float4) ----
  {
    const float4* WiF = (const float4*)Wih;
    float4* sWiF = (float4*)sWi;
#pragma unroll
    for (int n = 0; n < 8; ++n) {
      int idx = tid + 1024 * n;          // 0..8191 float4s
      int r = idx >> 8, c = idx & 255;
      int gr = (r >> 3) * HID + u0 + (r & 7);
      sWiF[idx] = WiF[(size_t)gr * 256 + c];
    }
  }

  // ---- prologue: W_hh + W_interm slices -> registers, PINNED ----
  float4 rwh[16], rwm[2];
#pragma unroll
  for (int it = 0; it < 16; ++it) rwh[it] = wh[q + 32 * it];
  rwm[0] = wm[bq];
  rwm[1] = wm[bq + 256];
#pragma unroll
  for (int it = 0; it < 16; ++it)
    asm volatile("" : "+v"(rwh[it].x), "+v"(rwh[it].y), "+v"(rwh[it].z), "+v"(rwh[it].w));
  asm volatile("" : "+v"(rwm[0].x), "+v"(rwm[0].y), "+v"(rwm[0].z), "+v"(rwm[0].w));
  asm volatile("" : "+v"(rwm[1].x), "+v"(rwm[1].y), "+v"(rwm[1].z), "+v"(rwm[1].w));

  const float4* sef = (const float4*)se;
  const float4* shf = (const float4*)sh;
  const float4* sWiF4 = (const float4*)sWi;

  int pred = 0;               // __START__
  float u_cur = U[tid];       // U[0] prefetched
  __syncthreads();            // sWi / sc / sh ready

  for (int t = 0; t < T_STEPS; ++t) {
    const unsigned ep = (unsigned)t + 1u;

    // ---- phase A: e from prefetched U + VT[pred]; gates from sh = h_{t-1} ----
    {
      float ev = u_cur + VT[(size_t)pred * EMB + tid];
      se[tid] = ev > 0.0f ? ev : 0.0f;
    }
    __syncthreads();                                  // (1) se ready
    float acc0 = 0.0f, acc1 = 0.0f;
#pragma unroll
    for (int it = 0; it < 8; ++it) {   // e part: 1024 (weights from LDS)
      float4 w = sWiF4[rt * 256 + q + 32 * it], x = sef[q + 32 * it];
      acc0 += w.x * x.x + w.y * x.y + w.z * x.z + w.w * x.w;
    }
#pragma unroll
    for (int it = 0; it < 16; ++it) {  // h part: 2048 (weights from VGPRs)
      float4 w = rwh[it], x = shf[q + 32 * it];
      acc1 += w.x * x.x + w.y * x.y + w.z * x.z + w.w * x.w;
    }
    float acc = acc0 + acc1;
#pragma unroll
    for (int d = 16; d > 0; d >>= 1) acc += __shfl_down(acc, d, 32);
    if (q == 0) sg[rt] = acc + bsum;
    __syncthreads();                                  // (2) sg ready; sh reads done
    if (tid < 8) {                      // LSTM pointwise; stamped h store
      float iv = sigf(sg[tid]);
      float fv = sigf(sg[8 + tid]);
      float gv = tanhf(sg[16 + tid]);
      float ov = sigf(sg[24 + tid]);
      float c = fv * sc[tid] + iv * gv;
      sc[tid] = c;
      // 8 lanes -> 8 DIFFERENT 2KB-strided lines: parallel at the MALL
      astore64(hp64 + tid * NBLK + b, pack(ep, ov * tanhf(c)));
    }

    // ---- poll-gather h_t: coalesced u64 loads, retry until epochs match ----
    if (tid < NBLK) {
      unsigned long long v[8];
      for (;;) {
        int ok = 1;
#pragma unroll
        for (int k = 0; k < 8; ++k) {
          v[k] = aload64(hp64 + k * NBLK + tid);
          ok &= epok(v[k], ep);
        }
        if (__all(ok)) break;
        __builtin_amdgcn_s_sleep(1);
      }
      float4 lo, hi;
      lo.x = val32(v[0]); lo.y = val32(v[1]); lo.z = val32(v[2]); lo.w = val32(v[3]);
      hi.x = val32(v[4]); hi.y = val32(v[5]); hi.z = val32(v[6]); hi.w = val32(v[7]);
      ((float4*)sh)[tid * 2] = lo;
      ((float4*)sh)[tid * 2 + 1] = hi;
    }
    float u_nxt = (t + 1 < T_STEPS) ? U[(size_t)(t + 1) * EMB + tid] : 0.0f;
    __syncthreads();                                  // (3) sh = h_t ready

    // ---- phase B: interm partials + tag partials ----
    {
      float a2 = 0.0f;
      float4 w = rwm[0], x = shf[bq];
      a2 += w.x * x.x + w.y * x.y + w.z * x.z + w.w * x.w;
      w = rwm[1]; x = shf[bq + 256];
      a2 += w.x * x.x + w.y * x.y + w.z * x.z + w.w * x.w;
#pragma unroll
      for (int d = 32; d > 0; d >>= 1) a2 += __shfl_down(a2, d, 64);
      if ((tid & 63) == 0) wpart[tid >> 6] = a2;
    }
    __syncthreads();                                  // (4) wpart ready
    if (tid < TAG) {                    // finish interm rows; stamped tp store
      float i0 = wpart[0] + wpart[1] + wpart[2] + wpart[3] + bi0;
      float i1 = wpart[4] + wpart[5] + wpart[6] + wpart[7] + bi1;
      float i2 = wpart[8] + wpart[9] + wpart[10] + wpart[11] + bi2;
      float i3 = wpart[12] + wpart[13] + wpart[14] + wpart[15] + bi3;
      i0 = i0 > 0.0f ? i0 : 0.0f;
      i1 = i1 > 0.0f ? i1 : 0.0f;
      i2 = i2 > 0.0f ? i2 : 0.0f;
      i3 = i3 > 0.0f ? i3 : 0.0f;
      // 16 lanes -> 16 DIFFERENT 2KB-strided lines: parallel at the MALL
      astore64(tp64 + tid * NBLK + b,
               pack(ep, wt0 * i0 + wt1 * i1 + wt2 * i2 + wt3 * i3));
    }

    // ---- poll-gather tag partials + reduce (wave w owns tag w) ----
    {
      const int w = tid >> 6, l = tid & 63;
      unsigned long long p0, p1, p2, p3;
      for (;;) {
        p0 = aload64(tp64 + w * NBLK + l);
        p1 = aload64(tp64 + w * NBLK + 64 + l);
        p2 = aload64(tp64 + w * NBLK + 128 + l);
        p3 = aload64(tp64 + w * NBLK + 192 + l);
        int ok = epok(p0, ep) & epok(p1, ep) & epok(p2, ep) & epok(p3, ep);
        if (__all(ok)) break;
        __builtin_amdgcn_s_sleep(1);
      }
      float v = val32(p0) + val32(p1) + val32(p2) + val32(p3);
#pragma unroll
      for (int d = 32; d > 0; d >>= 1) v += __shfl_down(v, d, 64);
      if (l == 0) stv[w] = v + btw;
    }
    __syncthreads();                                  // (5) stv ready

    // ---- phase C: argmax everywhere; softmax only on block 0 ----
    {
      int am = 0;
      float bv = stv[0];
#pragma unroll
      for (int k = 1; k < TAG; ++k) {
        if (stv[k] > bv) { bv = stv[k]; am = k; }
      }
      pred = am;
      if (b == 0) {
        if (tid < TAG) {
          float m = stv[0];
#pragma unroll
          for (int k = 1; k < TAG; ++k) m = fmaxf(m, stv[k]);
          float s = expf(stv[tid] - m);
#pragma unroll
          for (int msk = 8; msk > 0; msk >>= 1) s += __shfl_xor(s, msk, 16);
          float ls = logf(s);
          float lp = stv[tid] - m - ls;
          out[OUT_LOGP + t * TAG + tid] = lp;
          out[OUT_PROB + t * TAG + tid] = expf(lp);
        } else if (tid == TAG) {
          out[OUT_PRED + t] = (float)am;
        }
      }
      u_cur = u_nxt;
      // no trailing sync: stv next written behind syncs (1)-(4) of t+1
    }
  }
}

extern "C" void kernel_launch(void* const* d_in, const int* in_sizes, int n_in,
                              void* d_out, int out_size, void* d_ws, size_t ws_size,
                              hipStream_t stream) {
  const float* seq = (const float*)d_in[0];
  const float* W_embed = (const float*)d_in[1];
  const float* b_embed = (const float*)d_in[2];
  const float* W_ih = (const float*)d_in[3];
  const float* W_hh = (const float*)d_in[4];
  const float* b_ih = (const float*)d_in[5];
  const float* b_hh = (const float*)d_in[6];
  const float* W_interm = (const float*)d_in[7];
  const float* b_interm = (const float*)d_in[8];
  const float* W_tag = (const float*)d_in[9];
  const float* b_tag = (const float*)d_in[10];
  (void)in_sizes; (void)n_in; (void)out_size; (void)ws_size;

  // ws layout: [hp64 16K][tp64 32K][VT 64K][U 16M]
  const size_t hp_b = (size_t)8 * NBLK * 8;
  const size_t tp_b = (size_t)TAG * NBLK * 8;
  const size_t vt_b = (size_t)TAG * EMB * 4;

  char* ws = (char*)d_ws;
  unsigned long long* hp64 = (unsigned long long*)ws;
  unsigned long long* tp64 = (unsigned long long*)(ws + hp_b);
  float* VT = (float*)(ws + hp_b + tp_b);
  float* U = (float*)(ws + hp_b + tp_b + vt_b);
  float* out = (float*)d_out;

  // zero the stamped buffers: epoch 0 matches no step's epoch (1..4096),
  // restoring blocking semantics on every graph replay
  hipMemsetAsync(ws, 0, hp_b + tp_b, stream);

  hipLaunchKernelGGL(rnnss_vt_kernel, dim3((TAG * EMB) / 256), dim3(256), 0, stream,
                     W_embed, VT);
  hipLaunchKernelGGL(rnnss_uprep, dim3(T_STEPS / 64, EMB / 64), dim3(256), 0, stream,
                     seq, W_embed, b_embed, U);

  void* args[] = {
      (void*)&W_ih,    (void*)&W_hh,  (void*)&b_ih,  (void*)&b_hh,
      (void*)&W_interm,(void*)&b_interm, (void*)&W_tag, (void*)&b_tag,
      (void*)&U,       (void*)&VT,    (void*)&hp64,  (void*)&tp64,
      (void*)&out};
  hipLaunchCooperativeKernel((const void*)rnnss_persist, dim3(NBLK), dim3(NTHR),
                             args, 0, stream);
}